// Round 6
// baseline (18.265 us; speedup 1.0000x reference)
//
#include <hip/hip_runtime.h>
#include <math.h>

#define BN_EPS 1e-5f
#define LWIN   193     // 256 - 64 + 1 windows
#define WPB    16      // windows per B-block
#define NBL    13      // ceil(193/16)
#define CPOS   32      // owned positions per A-block
#define NCHK   8       // 256 / CPOS
#define LLOC   48      // A local slice: owned 32 + halo (l0 = sbase-3 .. +44)
#define ASTR   49      // A LDS row stride

typedef __attribute__((address_space(1))) const unsigned int gl_u32;
typedef __attribute__((address_space(3))) unsigned int lds_u32;

__device__ __forceinline__ float elu(float x) { return x > 0.f ? x : expm1f(x); }

// ---------------------------------------------------------------------------
// Kernel A: per-position window-invariant arrays, computed ONCE per position.
//   U[o][s]  = sum_c w2[o][c] eeg[c][s]
//   El[s]    = elu(A*U[s-1]+B*U[s]+C*U[s+1]+K)    (global zero-pad at 0/255)
//   P0g[s]   = 0.5*(elu(B*U[s]+C*U[s+1]+K) + El[s+1])   (window-edge pool term)
//   P2g[s]   = 0.5*(El[s]+El[s+1])
//   Qg[s]    = w30*P2[s-2]+w31*P2[s]+w32*P2[s+2]+b3
//   Efg[s]   = elu(sum_o W4t*Q + K4)
//   S5g[s]   = Ef[s]+Ef[s+2]+Ef[s+4]+Ef[s+6]+Ef[s+8]
// Block (b,cb) owns s in [32cb, 32cb+32); local slice i in [0,48), s = l0+i.
// Block (0,0) also publishes folded constants cst[512].
// ---------------------------------------------------------------------------
__global__ __launch_bounds__(256) void eegnet_stage1(
    const float* __restrict__ eeg,
    const float* __restrict__ c1w, const float* __restrict__ c1b,
    const float* __restrict__ bn1g, const float* __restrict__ bn1b,
    const float* __restrict__ bn1m, const float* __restrict__ bn1v,
    const float* __restrict__ w2,  const float* __restrict__ c2b,
    const float* __restrict__ bn2g, const float* __restrict__ bn2b,
    const float* __restrict__ bn2m, const float* __restrict__ bn2v,
    const float* __restrict__ c3w, const float* __restrict__ c3b,
    const float* __restrict__ c4w, const float* __restrict__ c4b,
    const float* __restrict__ bn3g, const float* __restrict__ bn3b,
    const float* __restrict__ bn3m, const float* __restrict__ bn3v,
    const float* __restrict__ linw, const float* __restrict__ linb,
    float* __restrict__ cstg, float* __restrict__ P0g, float* __restrict__ P2g,
    float* __restrict__ Efg, float* __restrict__ S5g)
{
    const int b     = blockIdx.x;
    const int cb    = blockIdx.y;
    const int sbase = cb * CPOS;
    const int l0    = sbase - 3;
    const int tid   = threadIdx.x;
    const int lane16 = tid & 15;
    const int grp16  = tid >> 4;

    __shared__ __align__(16) float Eg[64 * LLOC];   // stride 48, chunks stay in-row
    __shared__ float4 w2t4[64 * 4];
    __shared__ float  Ul[16][ASTR], El[16][ASTR], EZ[16][ASTR], P2[16][ASTR];
    __shared__ float  Ql[16][ASTR], Ef[16][ASTR], S5[16][ASTR], P0[16][ASTR];
    __shared__ float  cs[512];

    const float* ebase = eeg + b * 64 * 256;

    // ---- eeg -> LDS: 12 chunk-instrs (3/wave); per-element clamp fallback at edges ----
    {
        const int wv = tid >> 6, ln = tid & 63;
        #pragma unroll
        for (int j = 0; j < 3; ++j) {
            const int n    = wv * 3 + j;            // 0..11
            const int fidx = n * 256 + ln * 4;
            const int c    = fidx / LLOC;           // LLOC%4==0 -> chunk in-row
            const int i    = fidx - c * LLOC;
            const int s    = l0 + i;
            if (s >= 0 && s <= 252) {
                __builtin_amdgcn_global_load_lds((gl_u32*)(ebase + c * 256 + s),
                                                 (lds_u32*)&Eg[n * 256], 16, 0, 0);
            } else {
                const float* row = ebase + c * 256;
                const int e0 = s     < 0 ? 0 : (s     > 255 ? 255 : s);
                const int e1 = s + 1 < 0 ? 0 : (s + 1 > 255 ? 255 : s + 1);
                const int e2 = s + 2 < 0 ? 0 : (s + 2 > 255 ? 255 : s + 2);
                const int e3 = s + 3 < 0 ? 0 : (s + 3 > 255 ? 255 : s + 3);
                *reinterpret_cast<float4*>(&Eg[fidx]) =
                    make_float4(row[e0], row[e1], row[e2], row[e3]);
            }
        }
    }

    // ---- w2 -> LDS transposed ----
    {
        const int og = tid >> 6, c = tid & 63, o0 = og * 4;
        w2t4[c * 4 + og] = make_float4(w2[(o0    ) * 64 + c], w2[(o0 + 1) * 64 + c],
                                       w2[(o0 + 2) * 64 + c], w2[(o0 + 3) * 64 + c]);
    }

    // ---- fold constants (layout as r5) ----
    if (tid < 64) {
        const int f = tid & 15, q = tid >> 4;
        float s2p = 0.f;
        #pragma unroll
        for (int k = 0; k < 16; ++k) s2p += w2[f * 64 + q * 16 + k];
        s2p += __shfl_xor(s2p, 16);
        s2p += __shfl_xor(s2p, 32);
        if (tid < 16) {
            const int g = f >> 1;
            const float s1 = bn1g[g] / sqrtf(bn1v[g] + BN_EPS);
            const float o1 = bn1b[g] - bn1m[g] * s1;
            const float s2 = bn2g[f] / sqrtf(bn2v[f] + BN_EPS);
            const float o2 = bn2b[f] - bn2m[f] * s2;
            const float ss = s2 * s1;
            cs[      f] = ss * c1w[g * 3 + 0];
            cs[ 16 + f] = ss * c1w[g * 3 + 1];
            cs[ 32 + f] = ss * c1w[g * 3 + 2];
            cs[ 48 + f] = s2 * (fmaf(s1, c1b[g], o1) * s2p + c2b[f]) + o2;
            cs[ 64 + f] = c3w[f * 3 + 0];
            cs[ 80 + f] = c3w[f * 3 + 1];
            cs[ 96 + f] = c3w[f * 3 + 2];
            cs[112 + f] = c3b[f];
        }
    } else if (tid < 128) {
        const int j = tid - 64, f = j & 15, quad = j >> 4;
        const float s3 = bn3g[f] / sqrtf(bn3v[f] + BN_EPS);
        if (quad == 0)
            cs[128 + f] = fmaf(s3, c4b[f], bn3b[f] - bn3m[f] * s3);
        #pragma unroll
        for (int k = 0; k < 4; ++k) {
            const int o = quad * 4 + k;
            cs[144 + o * 16 + f] = s3 * c4w[f * 16 + o];
        }
    } else if (tid < 224) {
        cs[400 + tid - 128] = linw[tid - 128];
    } else if (tid == 224) {
        cs[496] = linb[0];
    } else if (tid < 240) {
        cs[tid + 272] = 0.f;   // cs[497..511]
    }
    __syncthreads();   // drains DMA + ds_writes + fold

    // ---- publish constants (block 0,0) ----
    if (b == 0 && cb == 0)
        for (int idx = tid; idx < 512; idx += 256) cstg[idx] = cs[idx];

    // ---- U phase: wave og owns channels 4og..4og+3; lanes 0..47 = positions ----
    {
        const int p = tid & 63, og = tid >> 6;
        if (p < LLOC) {
            float a0 = 0.f, a1 = 0.f, a2 = 0.f, a3 = 0.f;
            #pragma unroll 8
            for (int c = 0; c < 64; ++c) {
                const float4 w = w2t4[c * 4 + og];   // wave-uniform broadcast
                const float  e = Eg[c * LLOC + p];   // conflict-free
                a0 = fmaf(w.x, e, a0); a1 = fmaf(w.y, e, a1);
                a2 = fmaf(w.z, e, a2); a3 = fmaf(w.w, e, a3);
            }
            const int o0 = og * 4;
            Ul[o0    ][p] = a0; Ul[o0 + 1][p] = a1;
            Ul[o0 + 2][p] = a2; Ul[o0 + 3][p] = a3;
        }
    }
    __syncthreads();

    // ---- E + EZ phase ----
    #pragma unroll
    for (int k = 0; k < 3; ++k) {
        const int i = grp16 + 16 * k, sg = l0 + i, o = lane16;
        const float um = (sg >= 1)   ? Ul[o][i > 0 ? i - 1 : 0] : 0.f;
        const float uc = Ul[o][i];
        const float up = (sg <= 254) ? Ul[o][i < LLOC - 1 ? i + 1 : LLOC - 1] : 0.f;
        const float t  = fmaf(cs[16 + o], uc, fmaf(cs[32 + o], up, cs[48 + o]));
        El[o][i] = elu(fmaf(cs[o], um, t));
        EZ[o][i] = elu(t);
    }
    __syncthreads();

    // ---- P2 + P0 phase ----
    #pragma unroll
    for (int k = 0; k < 3; ++k) {
        const int i = grp16 + 16 * k, o = lane16;
        const int ip = i < LLOC - 1 ? i + 1 : LLOC - 1;
        P2[o][i] = 0.5f * (El[o][i] + El[o][ip]);
        P0[o][i] = 0.5f * (EZ[o][i] + El[o][ip]);
    }
    __syncthreads();

    // ---- Q phase ----
    #pragma unroll
    for (int k = 0; k < 3; ++k) {
        const int i = grp16 + 16 * k, o = lane16;
        const int im = i >= 2 ? i - 2 : 0;
        const int ip = i < LLOC - 2 ? i + 2 : LLOC - 1;
        Ql[o][i] = fmaf(cs[64 + o], P2[o][im],
                   fmaf(cs[80 + o], P2[o][i],
                   fmaf(cs[96 + o], P2[o][ip], cs[112 + o])));
    }
    __syncthreads();

    // ---- Ef phase ----
    #pragma unroll
    for (int k = 0; k < 3; ++k) {
        const int i = grp16 + 16 * k, f = lane16;
        float r = cs[128 + f];
        #pragma unroll
        for (int o = 0; o < 16; ++o)
            r = fmaf(cs[144 + o * 16 + f], Ql[o][i], r);
        Ef[f][i] = elu(r);
    }
    __syncthreads();

    // ---- S5 phase ----
    #pragma unroll
    for (int k = 0; k < 3; ++k) {
        const int i = grp16 + 16 * k, f = lane16;
        const int i2 = i + 2 < LLOC ? i + 2 : LLOC - 1;
        const int i4 = i + 4 < LLOC ? i + 4 : LLOC - 1;
        const int i6 = i + 6 < LLOC ? i + 6 : LLOC - 1;
        const int i8 = i + 8 < LLOC ? i + 8 : LLOC - 1;
        S5[f][i] = Ef[f][i] + Ef[f][i2] + Ef[f][i4] + Ef[f][i6] + Ef[f][i8];
    }
    __syncthreads();

    // ---- write owned slice [sbase, sbase+32): coalesced float2 per row ----
    {
        const int o = tid >> 4, j = tid & 15, i0 = 3 + 2 * j;   // i in [3,35)
        const int gidx = (b * 16 + o) * 256 + sbase + 2 * j;
        float2 v;
        v.x = P0[o][i0]; v.y = P0[o][i0 + 1]; *reinterpret_cast<float2*>(&P0g[gidx]) = v;
        v.x = P2[o][i0]; v.y = P2[o][i0 + 1]; *reinterpret_cast<float2*>(&P2g[gidx]) = v;
        v.x = Ef[o][i0]; v.y = Ef[o][i0 + 1]; *reinterpret_cast<float2*>(&Efg[gidx]) = v;
        v.x = S5[o][i0]; v.y = S5[o][i0 + 1]; *reinterpret_cast<float2*>(&S5g[gidx]) = v;
    }
}

// ---------------------------------------------------------------------------
// Kernel B: per-window readout. Block (b,wb) -> windows l in [16wb, 16wb+16).
// Stages cst + slices [L0,L0+20) of P0/P2/Ef and [L0,L0+68) of S5 via DMA,
// then Y1 (edge-corrected q0/q1) + Y2 (1x1 + elu + pool5-corrected linear).
// ---------------------------------------------------------------------------
__global__ __launch_bounds__(256) void eegnet_stage2(
    const float* __restrict__ cstg, const float* __restrict__ P0g,
    const float* __restrict__ P2g, const float* __restrict__ Efg,
    const float* __restrict__ S5g, float* __restrict__ out)
{
    const int b   = blockIdx.x;
    const int L0  = blockIdx.y * WPB;
    const int tid = threadIdx.x;
    const int lane16 = tid & 15;
    const int grp16  = tid >> 4;

    __shared__ __align__(16) float csB[512];
    __shared__ __align__(16) float P0l[16 * 20];
    __shared__ __align__(16) float P2l[16 * 20];
    __shared__ __align__(16) float Efl[16 * 20];
    __shared__ __align__(16) float S5l[16 * 68];
    __shared__ float q0s[16][17], q1s[16][17];

    // ---- stage: 13 DMA chunk-instrs, round-robin across 4 waves ----
    {
        const int wv = tid >> 6, ln = tid & 63;
        const int rowbase = b * 16;
        for (int t = wv; t < 13; t += 4) {
            if (t < 2) {
                __builtin_amdgcn_global_load_lds((gl_u32*)(cstg + t * 256 + ln * 4),
                                                 (lds_u32*)&csB[t * 256], 16, 0, 0);
            } else if (t < 8) {
                const int a = (t - 2) >> 1, half = (t - 2) & 1;
                const float* g = a == 0 ? P0g : (a == 1 ? P2g : Efg);
                float* l = a == 0 ? P0l : (a == 1 ? P2l : Efl);
                const int m = half * 64 + ln;            // chunk 0..79 (rows of 5)
                if (m < 80) {
                    const int row = m / 5, cc = m - row * 5;
                    __builtin_amdgcn_global_load_lds(
                        (gl_u32*)(g + (rowbase + row) * 256 + L0 + cc * 4),
                        (lds_u32*)&l[half * 256], 16, 0, 0);
                }
            } else {
                const int j = t - 8;                     // 0..4
                const int m = j * 64 + ln;               // chunk 0..271 (rows of 17)
                if (m < 272) {
                    const int row = m / 17, cc = m - row * 17;
                    __builtin_amdgcn_global_load_lds(
                        (gl_u32*)(S5g + (rowbase + row) * 256 + L0 + cc * 4),
                        (lds_u32*)&S5l[j * 256], 16, 0, 0);
                }
            }
        }
    }
    __syncthreads();

    // ---- Y1: per-window edge-corrected q0/q1 ----
    {
        const int w = grp16, o = lane16, l = L0 + w;
        if (l < LWIN) {
            const float P0v = P0l[o * 20 + w];
            const float pa  = P2l[o * 20 + w + 2], pb = P2l[o * 20 + w + 4];
            q0s[w][o] = fmaf(csB[80 + o], P0v, fmaf(csB[96 + o], pa, csB[112 + o]));
            q1s[w][o] = fmaf(csB[64 + o], P0v,
                        fmaf(csB[80 + o], pa, fmaf(csB[96 + o], pb, csB[112 + o])));
        }
    }
    __syncthreads();

    // ---- Y2: per-window output, reduce over f ----
    {
        const int w = grp16, f = lane16, l = L0 + w;
        float part = 0.f;
        if (l < LWIN) {
            float r0 = csB[128 + f], r1 = r0;
            #pragma unroll
            for (int o = 0; o < 16; ++o) {
                const float wt = csB[144 + o * 16 + f];
                r0 = fmaf(wt, q0s[w][o], r0);
                r1 = fmaf(wt, q1s[w][o], r1);
            }
            part = csB[400 + f * 6] *
                   (elu(r0) + elu(r1) - Efl[f * 20 + w] - Efl[f * 20 + w + 2]);
            #pragma unroll
            for (int g = 0; g < 6; ++g)
                part = fmaf(csB[400 + f * 6 + g], S5l[f * 68 + w + 10 * g], part);
        }
        part += __shfl_xor(part, 1);
        part += __shfl_xor(part, 2);
        part += __shfl_xor(part, 4);
        part += __shfl_xor(part, 8);
        if (f == 0 && l < LWIN) out[b * LWIN + l] = fmaf(0.2f, part, csB[496]);
    }
}

extern "C" void kernel_launch(void* const* d_in, const int* in_sizes, int n_in,
                              void* d_out, int out_size, void* d_ws, size_t ws_size,
                              hipStream_t stream) {
    const float* eeg  = (const float*)d_in[0];
    // d_in[1] = env, unused by the reference computation
    const float* c1w  = (const float*)d_in[2];
    const float* c1b  = (const float*)d_in[3];
    const float* bn1g = (const float*)d_in[4];
    const float* bn1b = (const float*)d_in[5];
    const float* bn1m = (const float*)d_in[6];
    const float* bn1v = (const float*)d_in[7];
    const float* w2   = (const float*)d_in[8];
    const float* c2b  = (const float*)d_in[9];
    const float* bn2g = (const float*)d_in[10];
    const float* bn2b = (const float*)d_in[11];
    const float* bn2m = (const float*)d_in[12];
    const float* bn2v = (const float*)d_in[13];
    const float* c3w  = (const float*)d_in[14];
    const float* c3b  = (const float*)d_in[15];
    const float* c4w  = (const float*)d_in[16];
    const float* c4b  = (const float*)d_in[17];
    const float* bn3g = (const float*)d_in[18];
    const float* bn3b = (const float*)d_in[19];
    const float* bn3m = (const float*)d_in[20];
    const float* bn3v = (const float*)d_in[21];
    const float* linw = (const float*)d_in[22];
    const float* linb = (const float*)d_in[23];

    float* cstg = (float*)d_ws;            // 512
    float* P0g  = cstg + 512;              // 16*16*256 each
    float* P2g  = P0g + 65536;
    float* Efg  = P2g + 65536;
    float* S5g  = Efg + 65536;             // +64 floats pad after (DMA tail overrun)

    eegnet_stage1<<<dim3(16, NCHK), 256, 0, stream>>>(
        eeg, c1w, c1b, bn1g, bn1b, bn1m, bn1v, w2, c2b,
        bn2g, bn2b, bn2m, bn2v, c3w, c3b, c4w, c4b,
        bn3g, bn3b, bn3m, bn3v, linw, linb,
        cstg, P0g, P2g, Efg, S5g);

    eegnet_stage2<<<dim3(16, NBL), 256, 0, stream>>>(
        cstg, P0g, P2g, Efg, S5g, (float*)d_out);
}